// Round 2
// baseline (249.410 us; speedup 1.0000x reference)
//
#include <hip/hip_runtime.h>

#define BATCH   131072
#define NHID    128
#define KDIM    256     // n_in + n_hid
#define BM      64      // batch rows per block
#define TPB     512     // 8 waves

typedef __bf16 bf16_t;
typedef __bf16 bf16x8 __attribute__((ext_vector_type(8)));
typedef float  f32x4  __attribute__((ext_vector_type(4)));

__device__ __forceinline__ float fsigmoid(float v) {
    // 1/(1+2^(-v*log2e)) ; v_exp_f32 + v_rcp_f32, no IEEE divide
    return __builtin_amdgcn_rcpf(1.0f + __builtin_amdgcn_exp2f(v * -1.44269504f));
}
__device__ __forceinline__ float ftanh(float v) {
    // tanh(v) = 1 - 2/(1+2^(2v*log2e)) ; inf-safe: rcp(inf)=0
    return __builtin_fmaf(-2.0f,
        __builtin_amdgcn_rcpf(1.0f + __builtin_amdgcn_exp2f(v * 2.88539008f)), 1.0f);
}

// Pack W4p[p][k] (bf16) with p = w*64 + t*16 + c  ->  gate t, output col j = w*16 + c.
// Puts all 4 gates of an output column into the same lane's 4 col-fragments.
__global__ void prep_kernel(const float* __restrict__ Wf, const float* __restrict__ Wi,
                            const float* __restrict__ Wc, const float* __restrict__ Wo,
                            const float* __restrict__ bfp, const float* __restrict__ bip,
                            const float* __restrict__ bcp, const float* __restrict__ bop,
                            const float* __restrict__ Wfc,
                            bf16_t* __restrict__ W4p, float* __restrict__ b4p,
                            bf16_t* __restrict__ Wfcb)
{
    int id = blockIdx.x * 256 + threadIdx.x;
    if (id < 512 * 256) {
        int p = id >> 8, k = id & 255;
        int w = p >> 6, t = (p >> 4) & 3, c = p & 15;
        int j = w * 16 + c;
        const float* W = (t == 0) ? Wf : (t == 1) ? Wi : (t == 2) ? Wc : Wo;
        W4p[id] = (bf16_t)W[j * 256 + k];
        if (k == 0) {
            const float* bs = (t == 0) ? bfp : (t == 1) ? bip : (t == 2) ? bcp : bop;
            b4p[p] = bs[j];
        }
    } else {
        int id2 = id - 512 * 256;
        if (id2 < 128 * 128) Wfcb[id2] = (bf16_t)Wfc[id2];
    }
}

__global__ __launch_bounds__(TPB, 4) void lstm_fused(
    const float* __restrict__ x, const float* __restrict__ hidden, const float* __restrict__ ctx,
    const bf16_t* __restrict__ W4p, const float* __restrict__ b4p,
    const bf16_t* __restrict__ Wfcb, const float* __restrict__ bfc,
    float* __restrict__ out, float* __restrict__ hid_out, float* __restrict__ ctx_out)
{
    // As: bf16 [64][256] XOR-swizzled (32 KB). Hs ([64][128], 16 KB) overlays As
    // after GEMM1 is done reading it (barrier-protected).
    __shared__ __align__(16) char lds[BM * KDIM * 2];
    char* As = lds;
    char* Hs = lds;

    const int tid  = threadIdx.x;
    const int lane = tid & 63;
    const int wv   = tid >> 6;     // 0..7
    const int l16  = lane & 15;
    const int lq   = lane >> 4;    // 0..3
    const int row0 = blockIdx.x * BM;
    const int jcol = wv * 16 + l16;

    // ---- stage A = [hidden | x] as bf16, swizzled (byte ^= (row&7)<<4) ----
    {
        const int r  = tid >> 3;   // 0..63
        const int cg = tid & 7;    // 32-col group
        const int c0 = cg * 32;
        const float* src = (c0 < NHID)
            ? (hidden + (size_t)(row0 + r) * NHID + c0)
            : (x      + (size_t)(row0 + r) * NHID + (c0 - NHID));
        #pragma unroll
        for (int g = 0; g < 4; ++g) {
            f32x4 v0 = *(const f32x4*)(src + g * 8);
            f32x4 v1 = *(const f32x4*)(src + g * 8 + 4);
            bf16x8 pk;
            pk[0] = (bf16_t)v0.x; pk[1] = (bf16_t)v0.y;
            pk[2] = (bf16_t)v0.z; pk[3] = (bf16_t)v0.w;
            pk[4] = (bf16_t)v1.x; pk[5] = (bf16_t)v1.y;
            pk[6] = (bf16_t)v1.z; pk[7] = (bf16_t)v1.w;
            const int cb = (c0 + g * 8) * 2;
            *(bf16x8*)(As + r * 512 + (cb ^ ((r & 7) << 4))) = pk;
        }
    }

    // ---- prefetch ctx (16 scalars) + biases BEFORE the barrier/GEMM1 ----
    // These HBM loads complete under GEMM1's ~1800 cycles of compute.
    const float* cp = ctx + (size_t)row0 * NHID + jcol;
    float ctxr[4][4];
    #pragma unroll
    for (int m = 0; m < 4; ++m)
        #pragma unroll
        for (int j = 0; j < 4; ++j)
            ctxr[m][j] = cp[(m * 16 + lq * 4 + j) * NHID];

    const float bfv = b4p[wv * 64 +  0 + l16];
    const float biv = b4p[wv * 64 + 16 + l16];
    const float bcv = b4p[wv * 64 + 32 + l16];
    const float bov = b4p[wv * 64 + 48 + l16];
    const float bo2 = bfc[jcol];

    __syncthreads();

    // ---- GEMM1: gates[64][512 packed] ; wave tile 64 rows x 64 packed cols ----
    f32x4 acc[4][4];   // [row frag m][gate t]
    #pragma unroll
    for (int m = 0; m < 4; ++m)
        #pragma unroll
        for (int t = 0; t < 4; ++t)
            acc[m][t] = f32x4{0.f, 0.f, 0.f, 0.f};

    const bf16_t* Bp = W4p + (wv * 64 + l16) * 256 + lq * 8;
    #pragma unroll
    for (int ks = 0; ks < 8; ++ks) {
        bf16x8 a[4], b[4];
        const int kb = ks * 64 + lq * 16;
        #pragma unroll
        for (int m = 0; m < 4; ++m) {
            const int r = m * 16 + l16;
            a[m] = *(const bf16x8*)(As + r * 512 + (kb ^ ((r & 7) << 4)));
        }
        #pragma unroll
        for (int t = 0; t < 4; ++t)
            b[t] = *(const bf16x8*)(Bp + t * 16 * 256 + ks * 32);
        #pragma unroll
        for (int m = 0; m < 4; ++m)
            #pragma unroll
            for (int t = 0; t < 4; ++t)
                acc[m][t] = __builtin_amdgcn_mfma_f32_16x16x32_bf16(a[m], b[t], acc[m][t], 0, 0, 0);
    }

    // ---- prefetch GEMM2 B-fragments (L2) so they're in flight during epilogue ----
    bf16x8 b2r[4];
    {
        const bf16_t* B2 = Wfcb + jcol * 128 + lq * 8;
        #pragma unroll
        for (int ks = 0; ks < 4; ++ks)
            b2r[ks] = *(const bf16x8*)(B2 + ks * 32);
    }

    // ---- fused LSTM elementwise; all 4 gates in-lane thanks to weight packing ----
    float* co = ctx_out + (size_t)row0 * NHID + jcol;
    float* ho = hid_out + (size_t)row0 * NHID + jcol;
    bf16_t hnb[16];

    #pragma unroll
    for (int m = 0; m < 4; ++m) {
        #pragma unroll
        for (int j = 0; j < 4; ++j) {
            const int off = (m * 16 + lq * 4 + j) * NHID;   // C/D: row=(lane>>4)*4+reg
            const float fv = fsigmoid(acc[m][0][j] + bfv);
            const float iv = fsigmoid(acc[m][1][j] + biv);
            const float cv = ftanh(acc[m][2][j] + bcv);
            const float ov = fsigmoid(acc[m][3][j] + bov);
            const float cn = fv * ctxr[m][j] + iv * cv;
            const float hn = ov * ftanh(cn);
            co[off] = cn;
            ho[off] = hn;
            hnb[m * 4 + j] = (bf16_t)hn;
        }
    }

    __syncthreads();   // all waves done reading As -> safe to overlay Hs

    #pragma unroll
    for (int m = 0; m < 4; ++m)
        #pragma unroll
        for (int j = 0; j < 4; ++j) {
            const int r = m * 16 + lq * 4 + j;
            *(bf16_t*)(Hs + r * 256 + ((jcol * 2) ^ ((r & 7) << 4))) = hnb[m * 4 + j];
        }

    __syncthreads();   // Hs visible

    // ---- GEMM2: out = hidden_new @ Wfc^T + bfc ; wave: 64 rows x 16 cols, K=128 ----
    f32x4 acc2[4];
    #pragma unroll
    for (int m = 0; m < 4; ++m) acc2[m] = f32x4{0.f, 0.f, 0.f, 0.f};

    #pragma unroll
    for (int ks = 0; ks < 4; ++ks) {
        const int kb = ks * 64 + lq * 16;
        #pragma unroll
        for (int m = 0; m < 4; ++m) {
            const int r = m * 16 + l16;
            bf16x8 a2 = *(const bf16x8*)(Hs + r * 256 + (kb ^ ((r & 7) << 4)));
            acc2[m] = __builtin_amdgcn_mfma_f32_16x16x32_bf16(a2, b2r[ks], acc2[m], 0, 0, 0);
        }
    }

    float* oo = out + (size_t)row0 * NHID + jcol;
    #pragma unroll
    for (int m = 0; m < 4; ++m)
        #pragma unroll
        for (int j = 0; j < 4; ++j) {
            const int off = (m * 16 + lq * 4 + j) * NHID;
            oo[off] = acc2[m][j] + bo2;
        }
}

extern "C" void kernel_launch(void* const* d_in, const int* in_sizes, int n_in,
                              void* d_out, int out_size, void* d_ws, size_t ws_size,
                              hipStream_t stream) {
    const float* x      = (const float*)d_in[0];
    const float* hidden = (const float*)d_in[1];
    const float* ctx    = (const float*)d_in[2];
    const float* Wf     = (const float*)d_in[3];
    const float* bfp    = (const float*)d_in[4];
    const float* Wi     = (const float*)d_in[5];
    const float* bip    = (const float*)d_in[6];
    const float* Wc     = (const float*)d_in[7];
    const float* bcp    = (const float*)d_in[8];
    const float* Wo     = (const float*)d_in[9];
    const float* bop    = (const float*)d_in[10];
    const float* Wfc    = (const float*)d_in[11];
    const float* bfc    = (const float*)d_in[12];

    bf16_t* W4p  = (bf16_t*)d_ws;                                   // 512*256*2 = 262144 B
    float*  b4p  = (float*)((char*)d_ws + 512 * 256 * 2);           // 2048 B
    bf16_t* Wfcb = (bf16_t*)((char*)d_ws + 512 * 256 * 2 + 2048);   // 32768 B

    prep_kernel<<<576, 256, 0, stream>>>(Wf, Wi, Wc, Wo, bfp, bip, bcp, bop, Wfc,
                                         W4p, b4p, Wfcb);

    float* outp = (float*)d_out;
    lstm_fused<<<BATCH / BM, TPB, 0, stream>>>(
        x, hidden, ctx, W4p, b4p, Wfcb, bfc,
        outp,
        outp + (size_t)BATCH * NHID,
        outp + 2 * (size_t)BATCH * NHID);
}

// Round 3
// 196.857 us; speedup vs baseline: 1.2670x; 1.2670x over previous
//
#include <hip/hip_runtime.h>

#define BATCH   131072
#define NHID    128
#define KDIM    256     // n_in + n_hid
#define BM      32      // batch rows per block
#define TPB     512     // 8 waves

typedef __bf16 bf16_t;
typedef __bf16 bf16x8 __attribute__((ext_vector_type(8)));
typedef float  f32x4  __attribute__((ext_vector_type(4)));

__device__ __forceinline__ float fsigmoid(float v) {
    // 1/(1+2^(-v*log2e)) ; v_exp_f32 + v_rcp_f32, no IEEE divide
    return __builtin_amdgcn_rcpf(1.0f + __builtin_amdgcn_exp2f(v * -1.44269504f));
}
__device__ __forceinline__ float ftanh(float v) {
    // tanh(v) = 1 - 2/(1+2^(2v*log2e)) ; inf-safe: rcp(inf)=0
    return __builtin_fmaf(-2.0f,
        __builtin_amdgcn_rcpf(1.0f + __builtin_amdgcn_exp2f(v * 2.88539008f)), 1.0f);
}

// Pack W4p[p][k] (bf16) with p = w*64 + t*16 + c  ->  gate t, output col j = w*16 + c.
// Puts all 4 gates of an output column into the same lane's 4 col-fragments.
__global__ void prep_kernel(const float* __restrict__ Wf, const float* __restrict__ Wi,
                            const float* __restrict__ Wc, const float* __restrict__ Wo,
                            const float* __restrict__ bfp, const float* __restrict__ bip,
                            const float* __restrict__ bcp, const float* __restrict__ bop,
                            const float* __restrict__ Wfc,
                            bf16_t* __restrict__ W4p, float* __restrict__ b4p,
                            bf16_t* __restrict__ Wfcb)
{
    int id = blockIdx.x * 256 + threadIdx.x;
    if (id < 512 * 256) {
        int p = id >> 8, k = id & 255;
        int w = p >> 6, t = (p >> 4) & 3, c = p & 15;
        int j = w * 16 + c;
        const float* W = (t == 0) ? Wf : (t == 1) ? Wi : (t == 2) ? Wc : Wo;
        W4p[id] = (bf16_t)W[j * 256 + k];
        if (k == 0) {
            const float* bs = (t == 0) ? bfp : (t == 1) ? bip : (t == 2) ? bcp : bop;
            b4p[p] = bs[j];
        }
    } else {
        int id2 = id - 512 * 256;
        if (id2 < 128 * 128) Wfcb[id2] = (bf16_t)Wfc[id2];
    }
}

__global__ __launch_bounds__(TPB) void lstm_fused(
    const float* __restrict__ x, const float* __restrict__ hidden, const float* __restrict__ ctx,
    const bf16_t* __restrict__ W4p, const float* __restrict__ b4p,
    const bf16_t* __restrict__ Wfcb, const float* __restrict__ bfc,
    float* __restrict__ out, float* __restrict__ hid_out, float* __restrict__ ctx_out)
{
    // As: bf16 [32][256] XOR-swizzled (16 KB). Hs ([32][128] bf16, 8 KB) overlays
    // As after GEMM1 is done reading it (barrier-protected).
    __shared__ __align__(16) char lds[BM * KDIM * 2];
    char* As = lds;
    char* Hs = lds;

    const int tid  = threadIdx.x;
    const int lane = tid & 63;
    const int wv   = tid >> 6;     // 0..7
    const int l16  = lane & 15;
    const int lq   = lane >> 4;    // 0..3
    const int row0 = blockIdx.x * BM;
    const int jcol = wv * 16 + l16;

    // ---- stage A = [hidden | x] as bf16, swizzled (byte ^= (row&7)<<4) ----
    // 32 rows x 256 cols; each thread handles 16 cols of one row.
    {
        const int r  = tid >> 4;   // 0..31
        const int cg = tid & 15;   // 16-col group
        const int c0 = cg * 16;
        const float* src = (c0 < NHID)
            ? (hidden + (size_t)(row0 + r) * NHID + c0)
            : (x      + (size_t)(row0 + r) * NHID + (c0 - NHID));
        #pragma unroll
        for (int g = 0; g < 2; ++g) {
            f32x4 v0 = *(const f32x4*)(src + g * 8);
            f32x4 v1 = *(const f32x4*)(src + g * 8 + 4);
            bf16x8 pk;
            pk[0] = (bf16_t)v0.x; pk[1] = (bf16_t)v0.y;
            pk[2] = (bf16_t)v0.z; pk[3] = (bf16_t)v0.w;
            pk[4] = (bf16_t)v1.x; pk[5] = (bf16_t)v1.y;
            pk[6] = (bf16_t)v1.z; pk[7] = (bf16_t)v1.w;
            const int cb = (c0 + g * 8) * 2;
            *(bf16x8*)(As + r * 512 + (cb ^ ((r & 7) << 4))) = pk;
        }
    }

    // ---- prefetch ctx (8 scalars) + biases BEFORE the barrier/GEMM1 ----
    const float* cp = ctx + (size_t)row0 * NHID + jcol;
    float ctxr[2][4];
    #pragma unroll
    for (int m = 0; m < 2; ++m)
        #pragma unroll
        for (int j = 0; j < 4; ++j)
            ctxr[m][j] = cp[(m * 16 + lq * 4 + j) * NHID];

    const float bfv = b4p[wv * 64 +  0 + l16];
    const float biv = b4p[wv * 64 + 16 + l16];
    const float bcv = b4p[wv * 64 + 32 + l16];
    const float bov = b4p[wv * 64 + 48 + l16];
    const float bo2 = bfc[jcol];

    __syncthreads();

    // ---- GEMM1: gates[32][512 packed] ; wave tile 32 rows x 64 packed cols ----
    f32x4 acc[2][4];   // [row frag m][gate t]
    #pragma unroll
    for (int m = 0; m < 2; ++m)
        #pragma unroll
        for (int t = 0; t < 4; ++t)
            acc[m][t] = f32x4{0.f, 0.f, 0.f, 0.f};

    const bf16_t* Bp = W4p + (wv * 64 + l16) * 256 + lq * 8;
    #pragma unroll
    for (int ks = 0; ks < 8; ++ks) {
        bf16x8 a[2], b[4];
        const int kb = ks * 64 + lq * 16;
        #pragma unroll
        for (int m = 0; m < 2; ++m) {
            const int r = m * 16 + l16;
            a[m] = *(const bf16x8*)(As + r * 512 + (kb ^ ((r & 7) << 4)));
        }
        #pragma unroll
        for (int t = 0; t < 4; ++t)
            b[t] = *(const bf16x8*)(Bp + t * 16 * 256 + ks * 32);
        #pragma unroll
        for (int m = 0; m < 2; ++m)
            #pragma unroll
            for (int t = 0; t < 4; ++t)
                acc[m][t] = __builtin_amdgcn_mfma_f32_16x16x32_bf16(a[m], b[t], acc[m][t], 0, 0, 0);
    }

    // ---- prefetch GEMM2 B-fragments (L2-resident) during epilogue ----
    bf16x8 b2r[4];
    {
        const bf16_t* B2 = Wfcb + jcol * 128 + lq * 8;
        #pragma unroll
        for (int ks = 0; ks < 4; ++ks)
            b2r[ks] = *(const bf16x8*)(B2 + ks * 32);
    }

    // ---- fused LSTM elementwise; all 4 gates in-lane thanks to weight packing ----
    float* co = ctx_out + (size_t)row0 * NHID + jcol;
    float* ho = hid_out + (size_t)row0 * NHID + jcol;
    bf16_t hnb[8];

    #pragma unroll
    for (int m = 0; m < 2; ++m) {
        #pragma unroll
        for (int j = 0; j < 4; ++j) {
            const int off = (m * 16 + lq * 4 + j) * NHID;   // C/D: row=(lane>>4)*4+reg
            const float fv = fsigmoid(acc[m][0][j] + bfv);
            const float iv = fsigmoid(acc[m][1][j] + biv);
            const float cv = ftanh(acc[m][2][j] + bcv);
            const float ov = fsigmoid(acc[m][3][j] + bov);
            const float cn = fv * ctxr[m][j] + iv * cv;
            const float hn = ov * ftanh(cn);
            co[off] = cn;
            ho[off] = hn;
            hnb[m * 4 + j] = (bf16_t)hn;
        }
    }

    __syncthreads();   // all waves done reading As -> safe to overlay Hs

    #pragma unroll
    for (int m = 0; m < 2; ++m)
        #pragma unroll
        for (int j = 0; j < 4; ++j) {
            const int r = m * 16 + lq * 4 + j;
            *(bf16_t*)(Hs + r * 256 + ((jcol * 2) ^ ((r & 7) << 4))) = hnb[m * 4 + j];
        }

    __syncthreads();   // Hs visible

    // ---- GEMM2: out = hidden_new @ Wfc^T + bfc ; wave: 32 rows x 16 cols, K=128 ----
    f32x4 acc2[2];
    #pragma unroll
    for (int m = 0; m < 2; ++m) acc2[m] = f32x4{0.f, 0.f, 0.f, 0.f};

    #pragma unroll
    for (int ks = 0; ks < 4; ++ks) {
        const int kb = ks * 64 + lq * 16;
        #pragma unroll
        for (int m = 0; m < 2; ++m) {
            const int r = m * 16 + l16;
            bf16x8 a2 = *(const bf16x8*)(Hs + r * 256 + (kb ^ ((r & 7) << 4)));
            acc2[m] = __builtin_amdgcn_mfma_f32_16x16x32_bf16(a2, b2r[ks], acc2[m], 0, 0, 0);
        }
    }

    float* oo = out + (size_t)row0 * NHID + jcol;
    #pragma unroll
    for (int m = 0; m < 2; ++m)
        #pragma unroll
        for (int j = 0; j < 4; ++j) {
            const int off = (m * 16 + lq * 4 + j) * NHID;
            oo[off] = acc2[m][j] + bo2;
        }
}

extern "C" void kernel_launch(void* const* d_in, const int* in_sizes, int n_in,
                              void* d_out, int out_size, void* d_ws, size_t ws_size,
                              hipStream_t stream) {
    const float* x      = (const float*)d_in[0];
    const float* hidden = (const float*)d_in[1];
    const float* ctx    = (const float*)d_in[2];
    const float* Wf     = (const float*)d_in[3];
    const float* bfp    = (const float*)d_in[4];
    const float* Wi     = (const float*)d_in[5];
    const float* bip    = (const float*)d_in[6];
    const float* Wc     = (const float*)d_in[7];
    const float* bcp    = (const float*)d_in[8];
    const float* Wo     = (const float*)d_in[9];
    const float* bop    = (const float*)d_in[10];
    const float* Wfc    = (const float*)d_in[11];
    const float* bfc    = (const float*)d_in[12];

    bf16_t* W4p  = (bf16_t*)d_ws;                                   // 512*256*2 = 262144 B
    float*  b4p  = (float*)((char*)d_ws + 512 * 256 * 2);           // 2048 B
    bf16_t* Wfcb = (bf16_t*)((char*)d_ws + 512 * 256 * 2 + 2048);   // 32768 B

    prep_kernel<<<576, 256, 0, stream>>>(Wf, Wi, Wc, Wo, bfp, bip, bcp, bop, Wfc,
                                         W4p, b4p, Wfcb);

    float* outp = (float*)d_out;
    lstm_fused<<<BATCH / BM, TPB, 0, stream>>>(
        x, hidden, ctx, W4p, b4p, Wfcb, bfc,
        outp,
        outp + (size_t)BATCH * NHID,
        outp + 2 * (size_t)BATCH * NHID);
}

// Round 4
// 122.268 us; speedup vs baseline: 2.0399x; 1.6100x over previous
//
#include <hip/hip_runtime.h>

#define BATCH   131072
#define NHID    128
#define KDIM    256     // n_in + n_hid
#define BM      32      // batch rows per tile
#define TPB     512     // 8 waves
#define NBLK    256     // persistent blocks (1 per CU)
#define NTILE   (BATCH / BM)     // 4096
#define TPBLK   (NTILE / NBLK)   // 16 tiles per block

typedef __bf16 bf16_t;
typedef __bf16 bf16x4 __attribute__((ext_vector_type(4)));
typedef __bf16 bf16x8 __attribute__((ext_vector_type(8)));
typedef float  f32x4  __attribute__((ext_vector_type(4)));

__device__ __forceinline__ float fsigmoid(float v) {
    return __builtin_amdgcn_rcpf(1.0f + __builtin_amdgcn_exp2f(v * -1.44269504f));
}
__device__ __forceinline__ float ftanh(float v) {
    return __builtin_fmaf(-2.0f,
        __builtin_amdgcn_rcpf(1.0f + __builtin_amdgcn_exp2f(v * 2.88539008f)), 1.0f);
}

// Pack W4p[p][k] (bf16) with p = w*64 + t*16 + c  ->  gate t, output col j = w*16 + c.
// Puts all 4 gates of an output column into the same lane's 4 col-fragments.
__global__ void prep_kernel(const float* __restrict__ Wf, const float* __restrict__ Wi,
                            const float* __restrict__ Wc, const float* __restrict__ Wo,
                            const float* __restrict__ bfp, const float* __restrict__ bip,
                            const float* __restrict__ bcp, const float* __restrict__ bop,
                            const float* __restrict__ Wfc,
                            bf16_t* __restrict__ W4p, float* __restrict__ b4p,
                            bf16_t* __restrict__ Wfcb)
{
    int id = blockIdx.x * 256 + threadIdx.x;
    if (id < 512 * 256) {
        int p = id >> 8, k = id & 255;
        int w = p >> 6, t = (p >> 4) & 3, c = p & 15;
        int j = w * 16 + c;
        const float* W = (t == 0) ? Wf : (t == 1) ? Wi : (t == 2) ? Wc : Wo;
        W4p[id] = (bf16_t)W[j * 256 + k];
        if (k == 0) {
            const float* bs = (t == 0) ? bfp : (t == 1) ? bip : (t == 2) ? bcp : bop;
            b4p[p] = bs[j];
        }
    } else {
        int id2 = id - 512 * 256;
        if (id2 < 128 * 128) Wfcb[id2] = (bf16_t)Wfc[id2];
    }
}

__global__ __launch_bounds__(TPB, 2) void lstm_fused(
    const float* __restrict__ x, const float* __restrict__ hidden, const float* __restrict__ ctx,
    const bf16_t* __restrict__ W4p, const float* __restrict__ b4p,
    const bf16_t* __restrict__ Wfcb, const float* __restrict__ bfc,
    float* __restrict__ out, float* __restrict__ hid_out, float* __restrict__ ctx_out)
{
    // As[2]: bf16 [32][256] XOR-swizzled (2x16 KB) ; Hs[2]: bf16 [32][128] (2x8 KB)
    __shared__ __align__(16) char lds[2 * 16384 + 2 * 8192];

    const int tid  = threadIdx.x;
    const int lane = tid & 63;
    const int wv   = tid >> 6;     // 0..7
    const int l16  = lane & 15;
    const int lq   = lane >> 4;    // 0..3
    const int jcol = wv * 16 + l16;
    const int tile0 = blockIdx.x * TPBLK;

    // stage-thread mapping: thread owns row r_s, four 4-float chunks at c_s*4 + i*64
    const int r_s = tid >> 4;      // 0..31
    const int c_s = tid & 15;
    const int swzS = (r_s & 7) << 4;
    const int swzA = (l16 & 7) << 4;

    // ---- resident weights: B1 = this wave's 64 packed gate-cols (128 VGPR) ----
    bf16x8 B1[32];   // [gt*8 + ks]
    {
        const bf16_t* Bp = W4p + (wv * 64 + l16) * 256 + lq * 8;
        #pragma unroll
        for (int gt = 0; gt < 4; ++gt)
            #pragma unroll
            for (int ks = 0; ks < 8; ++ks)
                B1[gt * 8 + ks] = *(const bf16x8*)(Bp + gt * 16 * 256 + ks * 32);
    }
    bf16x8 b2r[4];
    {
        const bf16_t* B2 = Wfcb + jcol * 128 + lq * 8;
        #pragma unroll
        for (int ks = 0; ks < 4; ++ks) b2r[ks] = *(const bf16x8*)(B2 + ks * 32);
    }
    const float bfv = b4p[wv * 64 +  0 + l16];
    const float biv = b4p[wv * 64 + 16 + l16];
    const float bcv = b4p[wv * 64 + 32 + l16];
    const float bov = b4p[wv * 64 + 48 + l16];
    const float bo2 = bfc[jcol];

    f32x4 sv0, sv1, sv2, sv3;   // in-flight stage regs (next tile's A)
    float ctxr[2][4];           // current tile's ctx

    // ---- prologue: stage tile0 -> As[0]; issue stage loads tile1; ctx(0) ----
    {
        const int grow = tile0 * BM + r_s;
        const float* hrow = hidden + (size_t)grow * NHID + c_s * 4;
        const float* xrow = x      + (size_t)grow * NHID + c_s * 4;
        sv0 = *(const f32x4*)(hrow);
        sv1 = *(const f32x4*)(hrow + 64);
        sv2 = *(const f32x4*)(xrow);
        sv3 = *(const f32x4*)(xrow + 64);
        char* A0 = lds;
        bf16x4 p0, p1, p2, p3;
        p0[0]=(bf16_t)sv0.x; p0[1]=(bf16_t)sv0.y; p0[2]=(bf16_t)sv0.z; p0[3]=(bf16_t)sv0.w;
        p1[0]=(bf16_t)sv1.x; p1[1]=(bf16_t)sv1.y; p1[2]=(bf16_t)sv1.z; p1[3]=(bf16_t)sv1.w;
        p2[0]=(bf16_t)sv2.x; p2[1]=(bf16_t)sv2.y; p2[2]=(bf16_t)sv2.z; p2[3]=(bf16_t)sv2.w;
        p3[0]=(bf16_t)sv3.x; p3[1]=(bf16_t)sv3.y; p3[2]=(bf16_t)sv3.z; p3[3]=(bf16_t)sv3.w;
        *(bf16x4*)(A0 + r_s * 512 + ((c_s * 8 +   0) ^ swzS)) = p0;
        *(bf16x4*)(A0 + r_s * 512 + ((c_s * 8 + 128) ^ swzS)) = p1;
        *(bf16x4*)(A0 + r_s * 512 + ((c_s * 8 + 256) ^ swzS)) = p2;
        *(bf16x4*)(A0 + r_s * 512 + ((c_s * 8 + 384) ^ swzS)) = p3;
    }
    {   // issue stage loads for tile 1
        const int grow = (tile0 + 1) * BM + r_s;
        const float* hrow = hidden + (size_t)grow * NHID + c_s * 4;
        const float* xrow = x      + (size_t)grow * NHID + c_s * 4;
        sv0 = *(const f32x4*)(hrow);
        sv1 = *(const f32x4*)(hrow + 64);
        sv2 = *(const f32x4*)(xrow);
        sv3 = *(const f32x4*)(xrow + 64);
    }
    {   // ctx for tile 0
        const float* cp = ctx + (size_t)(tile0 * BM) * NHID + jcol;
        #pragma unroll
        for (int m = 0; m < 2; ++m)
            #pragma unroll
            for (int j = 0; j < 4; ++j)
                ctxr[m][j] = cp[(m * 16 + lq * 4 + j) * NHID];
    }
    __syncthreads();

    for (int t = 0; t < TPBLK; ++t) {
        const int P = t & 1;
        const int row0 = (tile0 + t) * BM;
        char* Asb = lds + P * 16384;
        char* Hsb = lds + 32768 + P * 8192;

        // ---- GEMM1: B from registers, A from LDS ----
        f32x4 acc[2][4];
        #pragma unroll
        for (int m = 0; m < 2; ++m)
            #pragma unroll
            for (int gt = 0; gt < 4; ++gt)
                acc[m][gt] = f32x4{0.f, 0.f, 0.f, 0.f};

        #pragma unroll
        for (int ks = 0; ks < 8; ++ks) {
            const int kb = ks * 64 + lq * 16;
            bf16x8 a0 = *(const bf16x8*)(Asb + l16 * 512        + (kb ^ swzA));
            bf16x8 a1 = *(const bf16x8*)(Asb + (16 + l16) * 512 + (kb ^ swzA));
            #pragma unroll
            for (int gt = 0; gt < 4; ++gt) {
                acc[0][gt] = __builtin_amdgcn_mfma_f32_16x16x32_bf16(a0, B1[gt * 8 + ks], acc[0][gt], 0, 0, 0);
                acc[1][gt] = __builtin_amdgcn_mfma_f32_16x16x32_bf16(a1, B1[gt * 8 + ks], acc[1][gt], 0, 0, 0);
            }
        }

        // ---- fused LSTM elementwise (gates all in-lane) ----
        float* co = ctx_out + (size_t)row0 * NHID + jcol;
        float* ho = hid_out + (size_t)row0 * NHID + jcol;
        bf16_t hnb[8];
        #pragma unroll
        for (int m = 0; m < 2; ++m) {
            #pragma unroll
            for (int j = 0; j < 4; ++j) {
                const int off = (m * 16 + lq * 4 + j) * NHID;
                const float fv = fsigmoid(acc[m][0][j] + bfv);
                const float iv = fsigmoid(acc[m][1][j] + biv);
                const float cv = ftanh(acc[m][2][j] + bcv);
                const float ov = fsigmoid(acc[m][3][j] + bov);
                const float cn = fv * ctxr[m][j] + iv * cv;
                const float hn = ov * ftanh(cn);
                co[off] = cn;
                ho[off] = hn;
                hnb[m * 4 + j] = (bf16_t)hn;
            }
        }

        // ---- issue ctx loads for next tile (consumed next iteration) ----
        {
            const int tn = (t + 1 < TPBLK) ? t + 1 : TPBLK - 1;
            const float* cp = ctx + (size_t)((tile0 + tn) * BM) * NHID + jcol;
            #pragma unroll
            for (int m = 0; m < 2; ++m)
                #pragma unroll
                for (int j = 0; j < 4; ++j)
                    ctxr[m][j] = cp[(m * 16 + lq * 4 + j) * NHID];
        }

        // ---- write Hs (hidden_new, bf16, swizzled) ----
        #pragma unroll
        for (int m = 0; m < 2; ++m)
            #pragma unroll
            for (int j = 0; j < 4; ++j) {
                const int r = m * 16 + lq * 4 + j;
                *(bf16_t*)(Hsb + r * 256 + ((jcol * 2) ^ ((r & 7) << 4))) = hnb[m * 4 + j];
            }

        // ---- stage write: tile t+1 (loaded last iter) -> As[P^1] ----
        {
            char* An = lds + (1 - P) * 16384;
            bf16x4 p0, p1, p2, p3;
            p0[0]=(bf16_t)sv0.x; p0[1]=(bf16_t)sv0.y; p0[2]=(bf16_t)sv0.z; p0[3]=(bf16_t)sv0.w;
            p1[0]=(bf16_t)sv1.x; p1[1]=(bf16_t)sv1.y; p1[2]=(bf16_t)sv1.z; p1[3]=(bf16_t)sv1.w;
            p2[0]=(bf16_t)sv2.x; p2[1]=(bf16_t)sv2.y; p2[2]=(bf16_t)sv2.z; p2[3]=(bf16_t)sv2.w;
            p3[0]=(bf16_t)sv3.x; p3[1]=(bf16_t)sv3.y; p3[2]=(bf16_t)sv3.z; p3[3]=(bf16_t)sv3.w;
            *(bf16x4*)(An + r_s * 512 + ((c_s * 8 +   0) ^ swzS)) = p0;
            *(bf16x4*)(An + r_s * 512 + ((c_s * 8 + 128) ^ swzS)) = p1;
            *(bf16x4*)(An + r_s * 512 + ((c_s * 8 + 256) ^ swzS)) = p2;
            *(bf16x4*)(An + r_s * 512 + ((c_s * 8 + 384) ^ swzS)) = p3;
        }

        // ---- issue stage loads for tile t+2 ----
        {
            const int ts = (t + 2 < TPBLK) ? t + 2 : TPBLK - 1;
            const int grow = (tile0 + ts) * BM + r_s;
            const float* hrow = hidden + (size_t)grow * NHID + c_s * 4;
            const float* xrow = x      + (size_t)grow * NHID + c_s * 4;
            sv0 = *(const f32x4*)(hrow);
            sv1 = *(const f32x4*)(hrow + 64);
            sv2 = *(const f32x4*)(xrow);
            sv3 = *(const f32x4*)(xrow + 64);
        }

        __syncthreads();   // As[P^1] + Hs[P] ready for everyone

        // ---- GEMM2: out = hidden_new @ Wfc^T + bfc ----
        f32x4 acc2[2];
        acc2[0] = f32x4{0.f, 0.f, 0.f, 0.f};
        acc2[1] = f32x4{0.f, 0.f, 0.f, 0.f};
        #pragma unroll
        for (int ks = 0; ks < 4; ++ks) {
            const int kb = ks * 64 + lq * 16;
            bf16x8 a0 = *(const bf16x8*)(Hsb + l16 * 256        + (kb ^ swzA));
            bf16x8 a1 = *(const bf16x8*)(Hsb + (16 + l16) * 256 + (kb ^ swzA));
            acc2[0] = __builtin_amdgcn_mfma_f32_16x16x32_bf16(a0, b2r[ks], acc2[0], 0, 0, 0);
            acc2[1] = __builtin_amdgcn_mfma_f32_16x16x32_bf16(a1, b2r[ks], acc2[1], 0, 0, 0);
        }
        float* oo = out + (size_t)row0 * NHID + jcol;
        #pragma unroll
        for (int m = 0; m < 2; ++m)
            #pragma unroll
            for (int j = 0; j < 4; ++j)
                oo[(m * 16 + lq * 4 + j) * NHID] = acc2[m][j] + bo2;
    }
}

extern "C" void kernel_launch(void* const* d_in, const int* in_sizes, int n_in,
                              void* d_out, int out_size, void* d_ws, size_t ws_size,
                              hipStream_t stream) {
    const float* x      = (const float*)d_in[0];
    const float* hidden = (const float*)d_in[1];
    const float* ctx    = (const float*)d_in[2];
    const float* Wf     = (const float*)d_in[3];
    const float* bfp    = (const float*)d_in[4];
    const float* Wi     = (const float*)d_in[5];
    const float* bip    = (const float*)d_in[6];
    const float* Wc     = (const float*)d_in[7];
    const float* bcp    = (const float*)d_in[8];
    const float* Wo     = (const float*)d_in[9];
    const float* bop    = (const float*)d_in[10];
    const float* Wfc    = (const float*)d_in[11];
    const float* bfc    = (const float*)d_in[12];

    bf16_t* W4p  = (bf16_t*)d_ws;                                   // 262144 B
    float*  b4p  = (float*)((char*)d_ws + 512 * 256 * 2);           // 2048 B
    bf16_t* Wfcb = (bf16_t*)((char*)d_ws + 512 * 256 * 2 + 2048);   // 32768 B

    prep_kernel<<<576, 256, 0, stream>>>(Wf, Wi, Wc, Wo, bfp, bip, bcp, bop, Wfc,
                                         W4p, b4p, Wfcb);

    float* outp = (float*)d_out;
    lstm_fused<<<NBLK, TPB, 0, stream>>>(
        x, hidden, ctx, W4p, b4p, Wfcb, bfc,
        outp,
        outp + (size_t)BATCH * NHID,
        outp + 2 * (size_t)BATCH * NHID);
}